// Round 1
// baseline (683.687 us; speedup 1.0000x reference)
//
#include <hip/hip_runtime.h>

#define NB 512
#define NC 32
#define NT 8192
#define TP 1024   // NT / 8
#define NG 11

__global__ __launch_bounds__(256) void local_gnn_kernel(
    const float* __restrict__ x,
    const float* __restrict__ W,
    const float* __restrict__ bias,
    float* __restrict__ out)
{
    const int tid = blockIdx.x * 256 + threadIdx.x;
    const int b   = tid >> 10;        // / TP
    const int ot  = tid & (TP - 1);   // % TP
    const int t0  = ot << 3;          // * 8

    // channel -> group mapping (channels 7, 18, 25 are unused by any group)
    constexpr int NCH = 29;
    constexpr int CH[NCH]  = {0,1,2,3,4,5,6,8,9,10,11,12,13,14,15,
                              16,17,19,20,21,22,23,24,26,27,28,29,30,31};
    constexpr int GRP[NCH] = {0,0,1,1,2,2,6,7,7,8,8,9,10,10,8,
                              3,3,4,4,5,5,6,6,8,7,8,8,9,10};

    float acc[NG];
    #pragma unroll
    for (int g = 0; g < NG; ++g) acc[g] = 0.0f;

    const float* xb = x + (size_t)b * (NC * NT) + t0;

    #pragma unroll
    for (int i = 0; i < NCH; ++i) {
        const int c = CH[i];
        const float4 xv0 = *(const float4*)(xb + c * NT);
        const float4 xv1 = *(const float4*)(xb + c * NT + 4);
        const float4 wv0 = *(const float4*)(W + c * NT + t0);
        const float4 wv1 = *(const float4*)(W + c * NT + t0 + 4);
        const float bc = bias[c];
        float s;
        s  = fmaxf(xv0.x * wv0.x - bc, 0.0f);
        s += fmaxf(xv0.y * wv0.y - bc, 0.0f);
        s += fmaxf(xv0.z * wv0.z - bc, 0.0f);
        s += fmaxf(xv0.w * wv0.w - bc, 0.0f);
        s += fmaxf(xv1.x * wv1.x - bc, 0.0f);
        s += fmaxf(xv1.y * wv1.y - bc, 0.0f);
        s += fmaxf(xv1.z * wv1.z - bc, 0.0f);
        s += fmaxf(xv1.w * wv1.w - bc, 0.0f);
        acc[GRP[i]] += s;
    }

    // divisor = 8 (pool) * group size
    constexpr float INV[NG] = {1.f/16, 1.f/16, 1.f/16, 1.f/16, 1.f/16, 1.f/16,
                               1.f/24, 1.f/24, 1.f/48, 1.f/16, 1.f/24};

    float* ob = out + (size_t)b * (NG * TP) + ot;
    #pragma unroll
    for (int g = 0; g < NG; ++g)
        ob[g * TP] = acc[g] * INV[g];
}

extern "C" void kernel_launch(void* const* d_in, const int* in_sizes, int n_in,
                              void* d_out, int out_size, void* d_ws, size_t ws_size,
                              hipStream_t stream) {
    const float* x    = (const float*)d_in[0];
    const float* W    = (const float*)d_in[1];
    const float* bias = (const float*)d_in[2];
    float* out        = (float*)d_out;

    const int total  = NB * TP;             // 524288 threads
    const int block  = 256;
    const int grid   = total / block;       // 2048 blocks

    hipLaunchKernelGGL(local_gnn_kernel, dim3(grid), dim3(block), 0, stream,
                       x, W, bias, out);
}

// Round 2
// 683.594 us; speedup vs baseline: 1.0001x; 1.0001x over previous
//
#include <hip/hip_runtime.h>

#define NB 512
#define NC 32
#define NT 8192
#define TP 1024        // NT / 8 pooled windows
#define NG 11
#define TILE 64        // time-windows per block
#define NSLICE 4       // channel slices (one per wave)

typedef float f32x4 __attribute__((ext_vector_type(4)));

__global__ __launch_bounds__(256, 6) void local_gnn_kernel(
    const float* __restrict__ xg,
    const float* __restrict__ W,
    const float* __restrict__ bias,
    float* __restrict__ out)
{
    __shared__ float red[NG][NSLICE][TILE];   // 11*4*64*4 = 11264 B

    const int xw = threadIdx.x & (TILE - 1);  // time-window within tile
    const int y  = threadIdx.x >> 6;          // channel slice — wave-uniform
    const int bb = blockIdx.x >> 4;           // batch (TP/TILE = 16 tiles)
    const int tb = blockIdx.x & 15;           // tile index
    const int t0 = (tb * TILE + xw) * 8;      // first time sample of window

    const float* xb = xg + (size_t)bb * (NC * NT) + t0;
    const float* Wb = W + t0;

    float acc[NG];
    #pragma unroll
    for (int g = 0; g < NG; ++g) acc[g] = 0.0f;

#define DO_CH(c, g) do {                                                     \
    f32x4 xv0 = __builtin_nontemporal_load((const f32x4*)(xb + (c) * NT));    \
    f32x4 xv1 = __builtin_nontemporal_load((const f32x4*)(xb + (c) * NT + 4));\
    f32x4 wv0 = *(const f32x4*)(Wb + (c) * NT);                               \
    f32x4 wv1 = *(const f32x4*)(Wb + (c) * NT + 4);                           \
    const float bc = bias[c];                                                 \
    float s;                                                                  \
    s  = fmaxf(fmaf(xv0.x, wv0.x, -bc), 0.0f);                                \
    s += fmaxf(fmaf(xv0.y, wv0.y, -bc), 0.0f);                                \
    s += fmaxf(fmaf(xv0.z, wv0.z, -bc), 0.0f);                                \
    s += fmaxf(fmaf(xv0.w, wv0.w, -bc), 0.0f);                                \
    s += fmaxf(fmaf(xv1.x, wv1.x, -bc), 0.0f);                                \
    s += fmaxf(fmaf(xv1.y, wv1.y, -bc), 0.0f);                                \
    s += fmaxf(fmaf(xv1.z, wv1.z, -bc), 0.0f);                                \
    s += fmaxf(fmaf(xv1.w, wv1.w, -bc), 0.0f);                                \
    acc[g] += s;                                                              \
} while (0)

    // wave-uniform switch: lanes 0..63 -> y=0, etc. No divergence.
    switch (y) {
    case 0:
        DO_CH(0, 0); DO_CH(1, 0); DO_CH(2, 1); DO_CH(3, 1);
        DO_CH(4, 2); DO_CH(5, 2); DO_CH(6, 6); DO_CH(8, 7);
        break;
    case 1:
        DO_CH(9, 7);  DO_CH(10, 8); DO_CH(11, 8); DO_CH(12, 9);
        DO_CH(13, 10); DO_CH(14, 10); DO_CH(15, 8);
        break;
    case 2:
        DO_CH(16, 3); DO_CH(17, 3); DO_CH(19, 4); DO_CH(20, 4);
        DO_CH(21, 5); DO_CH(22, 5); DO_CH(23, 6);
        break;
    default:
        DO_CH(24, 6); DO_CH(26, 8); DO_CH(27, 7); DO_CH(28, 8);
        DO_CH(29, 8); DO_CH(30, 9); DO_CH(31, 10);
        break;
    }
#undef DO_CH

    // red[g][y][xw]: lanes vary xw -> consecutive addresses, conflict-free
    #pragma unroll
    for (int g = 0; g < NG; ++g)
        red[g][y][xw] = acc[g];

    __syncthreads();

    // group sizes {2,2,2,2,2,2,3,3,6,2,3}; divisor = 8 * size
    constexpr float INV[NG] = {1.f/16, 1.f/16, 1.f/16, 1.f/16, 1.f/16, 1.f/16,
                               1.f/24, 1.f/24, 1.f/48, 1.f/16, 1.f/24};

    float* ob = out + (size_t)bb * (NG * TP) + tb * TILE;
    #pragma unroll
    for (int base = 0; base < NG * TILE; base += 256) {
        const int idx = base + threadIdx.x;
        if (idx < NG * TILE) {
            const int g  = idx >> 6;        // wave-uniform per iteration
            const int x2 = idx & 63;
            const float s = red[g][0][x2] + red[g][1][x2] +
                            red[g][2][x2] + red[g][3][x2];
            ob[(size_t)g * TP + x2] = s * INV[g];
        }
    }
}

extern "C" void kernel_launch(void* const* d_in, const int* in_sizes, int n_in,
                              void* d_out, int out_size, void* d_ws, size_t ws_size,
                              hipStream_t stream) {
    const float* x    = (const float*)d_in[0];
    const float* W    = (const float*)d_in[1];
    const float* bias = (const float*)d_in[2];
    float* out        = (float*)d_out;

    const int grid = NB * (TP / TILE);   // 512 * 16 = 8192 blocks
    hipLaunchKernelGGL(local_gnn_kernel, dim3(grid), dim3(256), 0, stream,
                       x, W, bias, out);
}